// Round 1
// baseline (171.029 us; speedup 1.0000x reference)
//
#include <hip/hip_runtime.h>

#define HIDDEN 256
#define GAMMA_F 12.0f
#define BATCH 8

// ---------------------------------------------------------------------------
// Kernel A: stream the entity table once.
// r5 history: ILP staging / LDS-DMA / register pipelines neutral at ~46us,
// TLP 16->32 waves/CU also ~neutral (163.6 -> 163.97 total). Effective BW
// ~2.6 TB/s vs 6.9 TB/s sustained by the adjacent harness fills => the limit
// is the per-wave 6-deep dependent ds_swizzle chain (each link behind
// lgkmcnt(0)) with nothing in-wave to overlap it.
// r6 change: process a PAIR of consecutive entities per iteration and
// interleave the two reduction trees — entity B's 64-inst VALU distance
// block hides entity A's shuffle latency and vice versa. The two trees share
// the final 8/16/32 butterfly (17 DS ops/pair vs 20), 2 loads in flight, and
// the store becomes one full 64B line (lanes 0..15 -> entities e,e+1 x 8
// batches). Live ranges staggered: peak ~58 VGPR, keeps 32 waves/CU under
// __launch_bounds__(256,8).
// Reduction mapping (verified in prior rounds): stages 1,2,4 fold the 3
// batch bits into lane bits 0..2; after the merged xor-8 fold, lane l holds
// batch (l&7) of entity ((l>>3)&1); xor 16,32 complete the group sum.
// ---------------------------------------------------------------------------
__global__ __launch_bounds__(256, 8) void kge_dist_kernel(
    const float* __restrict__ ent,
    const float* __restrict__ rel,
    const int*  __restrict__ pos,
    float* __restrict__ dist,   // [nent, 8]
    int nent, int nwaves)
{
    const int lane = threadIdx.x & 63;
    const int wave_gid = (blockIdx.x * 256 + threadIdx.x) >> 6;

    // hr[b] = head_b + rel_b at dims [4*lane, 4*lane+4) — 32 VGPRs, once
    float4 hr[BATCH];
    #pragma unroll
    for (int b = 0; b < BATCH; ++b) {
        const int hidx = pos[b * 3 + 0];
        const int ridx = pos[b * 3 + 1];
        const float4 h4 = *(const float4*)(ent + (size_t)hidx * HIDDEN + lane * 4);
        const float4 r4 = *(const float4*)(rel + (size_t)ridx * HIDDEN + lane * 4);
        hr[b] = make_float4(h4.x + r4.x, h4.y + r4.y, h4.z + r4.z, h4.w + r4.w);
    }

    const bool p1 = lane & 1;
    const bool p2 = (lane >> 1) & 1;
    const bool p4 = (lane >> 2) & 1;
    const bool p8 = (lane >> 3) & 1;

    // virtual pair count: odd-nent tail maps onto pair (nent-2, nent-1);
    // the duplicated entity gets identical bits rewritten — benign.
    const int npairs_v = (nent + 1) >> 1;
    for (int p = wave_gid; p < npairs_v; p += nwaves) {
        int e0 = 2 * p;
        if (e0 > nent - 2) e0 = nent - 2;

        const float* row = ent + (size_t)e0 * HIDDEN + lane * 4;
        const float4 ta = *(const float4*)row;
        const float4 tb = *(const float4*)(row + HIDDEN);

        // ---- entity A: distance partials
        float accA[BATCH];
        #pragma unroll
        for (int b = 0; b < BATCH; ++b) {
            accA[b] = fabsf(hr[b].x - ta.x) + fabsf(hr[b].y - ta.y)
                    + fabsf(hr[b].z - ta.z) + fabsf(hr[b].w - ta.w);
        }

        // ---- stage1 A (4 shfl) — lgkm wait overlapped by dist B below
        float vA[4];
        #pragma unroll
        for (int k = 0; k < 4; ++k) {
            const float keep = p1 ? accA[2 * k + 1] : accA[2 * k];
            const float give = p1 ? accA[2 * k]     : accA[2 * k + 1];
            vA[k] = keep + __shfl_xor(give, 1, 64);
        }

        // ---- entity B: distance partials (64 VALU insts hide A's DS chain)
        float accB[BATCH];
        #pragma unroll
        for (int b = 0; b < BATCH; ++b) {
            accB[b] = fabsf(hr[b].x - tb.x) + fabsf(hr[b].y - tb.y)
                    + fabsf(hr[b].z - tb.z) + fabsf(hr[b].w - tb.w);
        }

        // ---- stage2 A
        float wA[2];
        #pragma unroll
        for (int k = 0; k < 2; ++k) {
            const float keep = p2 ? vA[2 * k + 1] : vA[2 * k];
            const float give = p2 ? vA[2 * k]     : vA[2 * k + 1];
            wA[k] = keep + __shfl_xor(give, 2, 64);
        }

        // ---- stage1 B
        float vB[4];
        #pragma unroll
        for (int k = 0; k < 4; ++k) {
            const float keep = p1 ? accB[2 * k + 1] : accB[2 * k];
            const float give = p1 ? accB[2 * k]     : accB[2 * k + 1];
            vB[k] = keep + __shfl_xor(give, 1, 64);
        }

        // ---- stage3 A
        float sA;
        {
            const float keep = p4 ? wA[1] : wA[0];
            const float give = p4 ? wA[0] : wA[1];
            sA = keep + __shfl_xor(give, 4, 64);
        }

        // ---- stage2 B
        float wB[2];
        #pragma unroll
        for (int k = 0; k < 2; ++k) {
            const float keep = p2 ? vB[2 * k + 1] : vB[2 * k];
            const float give = p2 ? vB[2 * k]     : vB[2 * k + 1];
            wB[k] = keep + __shfl_xor(give, 2, 64);
        }

        // ---- stage3 B
        float sB;
        {
            const float keep = p4 ? wB[1] : wB[0];
            const float give = p4 ? wB[0] : wB[1];
            sB = keep + __shfl_xor(give, 4, 64);
        }

        // ---- merged tail: fold entity bit into lane bit 3, then butterfly
        {
            const float keep = p8 ? sB : sA;
            const float give = p8 ? sA : sB;
            float t = keep + __shfl_xor(give, 8, 64);
            t += __shfl_xor(t, 16, 64);
            t += __shfl_xor(t, 32, 64);
            // lane l<16 holds batch (l&7) of entity e0 + ((l>>3)&1):
            // one contiguous 64B line per pair.
            if (lane < 16)
                dist[(size_t)e0 * BATCH + lane] = GAMMA_F - t;
        }
    }
}

// ---------------------------------------------------------------------------
// Kernel B (unchanged this round): out[b,n] = dist[neg[b,n]*8 + b].
// dist (3.2MB) is L2-resident per XCD. 2 outputs/thread.
// ---------------------------------------------------------------------------
__global__ __launch_bounds__(256) void kge_gather_kernel(
    const int*  __restrict__ neg,
    const float* __restrict__ dist,
    float* __restrict__ out,
    int nneg)
{
    const int b = blockIdx.y;
    const int n = (blockIdx.x * 256 + threadIdx.x) * 2;
    if (n + 1 < nneg) {
        const int2 idx = *(const int2*)(neg + (size_t)b * nneg + n);
        float2 r;
        r.x = dist[(size_t)idx.x * BATCH + b];
        r.y = dist[(size_t)idx.y * BATCH + b];
        *(float2*)(out + (size_t)b * nneg + n) = r;
    } else if (n < nneg) {
        out[(size_t)b * nneg + n] =
            dist[(size_t)neg[(size_t)b * nneg + n] * BATCH + b];
    }
}

extern "C" void kernel_launch(void* const* d_in, const int* in_sizes, int n_in,
                              void* d_out, int out_size, void* d_ws, size_t ws_size,
                              hipStream_t stream) {
    const float* ent = (const float*)d_in[0];   // [100000, 256] f32
    const float* rel = (const float*)d_in[1];   // [500, 256]    f32
    const int*   pos = (const int*)d_in[2];     // [8, 3]        int32
    const int*   neg = (const int*)d_in[3];     // [8, 100000]   int32
    float* out = (float*)d_out;                 // [8, 100000]   f32

    const int nent = in_sizes[0] / HIDDEN;      // 100000
    const int nneg = in_sizes[3] / BATCH;       // 100000
    float* dist = (float*)d_ws;                 // 3.2 MB (ws is larger)

    // 2048 blocks = 8 blocks/CU = 32 waves/CU (needs VGPR<=64 -> bounds(256,8))
    const int nblocks = 2048;
    const int nwaves = nblocks * 4;
    kge_dist_kernel<<<nblocks, 256, 0, stream>>>(ent, rel, pos, dist,
                                                 nent, nwaves);

    const int npairs = (nneg + 1) / 2;
    dim3 gridB((npairs + 255) / 256, BATCH);
    kge_gather_kernel<<<gridB, 256, 0, stream>>>(neg, dist, out, nneg);
}

// Round 3
// 170.353 us; speedup vs baseline: 1.0040x; 1.0040x over previous
//
#include <hip/hip_runtime.h>

#define HIDDEN 256
#define GAMMA_F 12.0f
#define BATCH 8

// ---------------------------------------------------------------------------
// Kernel A: stream the entity table once.
// History: r1-r4 ILP staging / LDS-DMA / reg pipelines neutral (~46us);
// r5 TLP 16->32 waves/CU neutral; r6 paired-tree interleave +4us. All kept
// ~10 cross-lane DS ops/entity -> the per-CU LDS pipe is the saturated
// resource (390 ent/CU x 10 DS x ~15-25 eff cyc ~ 40us, matching measurement
// while VALU ~8us and HBM ~17us sit under-used).
// r8: reduction entirely on the VALU pipe — ZERO DS ops per entity.
// Batch bits fold into lane bits {0,1,5}:
//   xor1  -> DPP quad_perm [1,0,3,2] (0xB1)
//   xor2  -> DPP quad_perm [2,3,0,1] (0x4E)
//   xor32 -> v_permlane32_swap_b32, both-sum form: with a=b=give,
//            r0[i]+r1[i] = give(i)+give(i^32) under EITHER swap convention;
//            final = keep + (both - give)  (~1ulp, tol=2.0)
//   sum lane-bit2 -> DPP row_shl:4 (0x104, bound_ctrl: OOB lanes read 0)
//   sum lane-bit3 -> DPP row_shl:8 (0x108)   [data flows toward lane 0]
//   sum lane-bit4 -> v_permlane16_swap_b32 both-sum: r0+r1 = u(i)+u(i^16)
// After the tree, lanes {0-3,32-35} hold batch (l&3)+4*(l>>5); 32B/entity
// written as two 16B segments. Launch unchanged: 2048 blocks,
// __launch_bounds__(256,8), ~56 VGPR -> 32 waves/CU.
// ---------------------------------------------------------------------------

typedef unsigned int v2u __attribute__((ext_vector_type(2)));

// keep + dpp(give): CTRL/BC are template params -> integer constant exprs,
// which __builtin_amdgcn_update_dpp requires (r7 compile fix).
template <int CTRL, bool BC>
__device__ __forceinline__ float dpp_fold_add(float keep, float give) {
    const int g = __builtin_amdgcn_update_dpp(0, __float_as_int(give),
                                              CTRL, 0xf, 0xf, BC);
    return keep + __int_as_float(g);
}

__global__ __launch_bounds__(256, 8) void kge_dist_kernel(
    const float* __restrict__ ent,
    const float* __restrict__ rel,
    const int*  __restrict__ pos,
    float* __restrict__ dist,   // [nent, 8]
    int nent, int nwaves)
{
    const int lane = threadIdx.x & 63;
    const int wave_gid = (blockIdx.x * 256 + threadIdx.x) >> 6;

    // hr[b] = head_b + rel_b at dims [4*lane, 4*lane+4) — 32 VGPRs, once
    float4 hr[BATCH];
    #pragma unroll
    for (int b = 0; b < BATCH; ++b) {
        const int hidx = pos[b * 3 + 0];
        const int ridx = pos[b * 3 + 1];
        const float4 h4 = *(const float4*)(ent + (size_t)hidx * HIDDEN + lane * 4);
        const float4 r4 = *(const float4*)(rel + (size_t)ridx * HIDDEN + lane * 4);
        hr[b] = make_float4(h4.x + r4.x, h4.y + r4.y, h4.z + r4.z, h4.w + r4.w);
    }

    const bool p1  = lane & 1;          // batch bit 0 <- lane bit 0
    const bool p2  = (lane >> 1) & 1;   // batch bit 1 <- lane bit 1
    const bool p32 = lane >= 32;        // batch bit 2 <- lane bit 5

    for (int e = wave_gid; e < nent; e += nwaves) {
        const float4 t4 = *(const float4*)(ent + (size_t)e * HIDDEN + lane * 4);

        float acc[BATCH];
        #pragma unroll
        for (int b = 0; b < BATCH; ++b) {
            acc[b] = fabsf(hr[b].x - t4.x) + fabsf(hr[b].y - t4.y)
                   + fabsf(hr[b].z - t4.z) + fabsf(hr[b].w - t4.w);
        }

        // ---- fold batch bit 0 into lane bit 0 (quad_perm xor1)
        float v[4];
        #pragma unroll
        for (int k = 0; k < 4; ++k) {
            const float keep = p1 ? acc[2 * k + 1] : acc[2 * k];
            const float give = p1 ? acc[2 * k]     : acc[2 * k + 1];
            v[k] = dpp_fold_add<0xB1, false>(keep, give);   // [1,0,3,2]
        }

        // ---- fold batch bit 1 into lane bit 1 (quad_perm xor2)
        float w[2];
        #pragma unroll
        for (int k = 0; k < 2; ++k) {
            const float keep = p2 ? v[2 * k + 1] : v[2 * k];
            const float give = p2 ? v[2 * k]     : v[2 * k + 1];
            w[k] = dpp_fold_add<0x4E, false>(keep, give);   // [2,3,0,1]
        }

        // ---- fold batch bit 2 into lane bit 5 (permlane32_swap, both-sum)
        float u;
        {
            const float keep = p32 ? w[1] : w[0];
            const float give = p32 ? w[0] : w[1];
#if __has_builtin(__builtin_amdgcn_permlane32_swap)
            const v2u r = __builtin_amdgcn_permlane32_swap(
                __float_as_uint(give), __float_as_uint(give), false, false);
            const float both = __uint_as_float(r[0]) + __uint_as_float(r[1]);
            u = keep + (both - give);    // = keep + give(l^32)
#else
            u = keep + __shfl_xor(give, 32, 64);
#endif
        }

        // ---- sum over lane bit 2 (row_shl:4, toward lane 0, OOB->0)
        u = dpp_fold_add<0x104, true>(u, u);
        // ---- sum over lane bit 3 (row_shl:8)
        u = dpp_fold_add<0x108, true>(u, u);
        // ---- sum over lane bit 4 (permlane16_swap, both-sum = u + u^16)
        {
#if __has_builtin(__builtin_amdgcn_permlane16_swap)
            const v2u r = __builtin_amdgcn_permlane16_swap(
                __float_as_uint(u), __float_as_uint(u), false, false);
            u = __uint_as_float(r[0]) + __uint_as_float(r[1]);
#else
            const int x = __builtin_amdgcn_ds_swizzle(__float_as_int(u), 0x401F);
            u += __int_as_float(x);
#endif
        }

        // lanes {0-3, 32-35} hold batch (l&3) + 4*(l>>5): 32B per entity
        if ((lane & 28) == 0)
            dist[(size_t)e * BATCH + (lane & 3) + ((lane >> 5) << 2)] =
                GAMMA_F - u;
    }
}

// ---------------------------------------------------------------------------
// Kernel B (unchanged): out[b,n] = dist[neg[b,n]*8 + b]. dist (3.2MB) is
// L2-resident. 2 outputs/thread: int2 index load, 2 gathers, float2 store.
// ---------------------------------------------------------------------------
__global__ __launch_bounds__(256) void kge_gather_kernel(
    const int*  __restrict__ neg,
    const float* __restrict__ dist,
    float* __restrict__ out,
    int nneg)
{
    const int b = blockIdx.y;
    const int n = (blockIdx.x * 256 + threadIdx.x) * 2;
    if (n + 1 < nneg) {
        const int2 idx = *(const int2*)(neg + (size_t)b * nneg + n);
        float2 r;
        r.x = dist[(size_t)idx.x * BATCH + b];
        r.y = dist[(size_t)idx.y * BATCH + b];
        *(float2*)(out + (size_t)b * nneg + n) = r;
    } else if (n < nneg) {
        out[(size_t)b * nneg + n] =
            dist[(size_t)neg[(size_t)b * nneg + n] * BATCH + b];
    }
}

extern "C" void kernel_launch(void* const* d_in, const int* in_sizes, int n_in,
                              void* d_out, int out_size, void* d_ws, size_t ws_size,
                              hipStream_t stream) {
    const float* ent = (const float*)d_in[0];   // [100000, 256] f32
    const float* rel = (const float*)d_in[1];   // [500, 256]    f32
    const int*   pos = (const int*)d_in[2];     // [8, 3]        int32
    const int*   neg = (const int*)d_in[3];     // [8, 100000]   int32
    float* out = (float*)d_out;                 // [8, 100000]   f32

    const int nent = in_sizes[0] / HIDDEN;      // 100000
    const int nneg = in_sizes[3] / BATCH;       // 100000
    float* dist = (float*)d_ws;                 // 3.2 MB (ws is larger)

    // 2048 blocks = 8 blocks/CU = 32 waves/CU (VGPR<=64 via bounds(256,8))
    const int nblocks = 2048;
    const int nwaves = nblocks * 4;
    kge_dist_kernel<<<nblocks, 256, 0, stream>>>(ent, rel, pos, dist,
                                                 nent, nwaves);

    const int npairs = (nneg + 1) / 2;
    dim3 gridB((npairs + 255) / 256, BATCH);
    kge_gather_kernel<<<gridB, 256, 0, stream>>>(neg, dist, out, nneg);
}

// Round 4
// 164.072 us; speedup vs baseline: 1.0424x; 1.0383x over previous
//
#include <hip/hip_runtime.h>

#define HIDDEN 256
#define GAMMA_F 12.0f
#define BATCH 8

// ---------------------------------------------------------------------------
// Kernel A: stream the entity table once — PURE TLP variant (r5 structure,
// reverted after r6/r8 experiments).
// Experiment ledger across sessions:
//   r1-r4: multi-row staging / LDS-DMA double-buffer / register pipeline —
//          all neutral (~46us attributed);
//   r5:    16->32 waves/CU (this code) — best measured totals 163.6, 163.97;
//   r6:    paired-entity interleaved trees — 171.0 (regression);
//   r8:    zero-DS DPP/permlane reduction — 170.4 (no change vs r6).
// Conclusion: kernel A's duration is invariant to ILP, TLP, DS-op count and
// reduction pipe => it is at its structural floor; the timed total is
// dominated by harness poison fills (2 x ~59.5us at 85-86% HBM peak) plus
// small reset dispatches. This r5 structure is the twice-validated best.
// Lane layout: lane covers dims [4*lane, 4*lane+4) — one float4 load inst
// moves one full 1KB row of unique contiguous data.
// Reduction (verified r4/r5): merge-tree — offsets 1,2,4 fold the 3 batch
// bits into lane bits 0..2, offsets 8,16,32 butterfly; lane l ends with the
// complete sum for batch l&7; lanes 0..7 store 32B contiguous.
// ---------------------------------------------------------------------------
__global__ __launch_bounds__(256, 8) void kge_dist_kernel(
    const float* __restrict__ ent,
    const float* __restrict__ rel,
    const int*  __restrict__ pos,
    float* __restrict__ dist,   // [nent, 8]
    int nent, int nwaves)
{
    const int lane = threadIdx.x & 63;
    const int wave_gid = (blockIdx.x * 256 + threadIdx.x) >> 6;

    // hr[b] = head_b + rel_b at dims [4*lane, 4*lane+4) — 32 VGPRs, once
    float4 hr[BATCH];
    #pragma unroll
    for (int b = 0; b < BATCH; ++b) {
        const int hidx = pos[b * 3 + 0];
        const int ridx = pos[b * 3 + 1];
        const float4 h4 = *(const float4*)(ent + (size_t)hidx * HIDDEN + lane * 4);
        const float4 r4 = *(const float4*)(rel + (size_t)ridx * HIDDEN + lane * 4);
        hr[b] = make_float4(h4.x + r4.x, h4.y + r4.y, h4.z + r4.z, h4.w + r4.w);
    }

    for (int e = wave_gid; e < nent; e += nwaves) {
        const float4 t4 = *(const float4*)(ent + (size_t)e * HIDDEN + lane * 4);

        float acc[BATCH];
        #pragma unroll
        for (int b = 0; b < BATCH; ++b) {
            acc[b] = fabsf(hr[b].x - t4.x) + fabsf(hr[b].y - t4.y)
                   + fabsf(hr[b].z - t4.z) + fabsf(hr[b].w - t4.w);
        }

        // fold batch bits into lane bits 0..2
        float v[4];
        {
            const bool p = lane & 1;
            #pragma unroll
            for (int k = 0; k < 4; ++k) {
                const float keep = p ? acc[2 * k + 1] : acc[2 * k];
                const float give = p ? acc[2 * k]     : acc[2 * k + 1];
                v[k] = keep + __shfl_xor(give, 1, 64);
            }
        }
        float w2[2];
        {
            const bool p = (lane >> 1) & 1;
            #pragma unroll
            for (int k = 0; k < 2; ++k) {
                const float keep = p ? v[2 * k + 1] : v[2 * k];
                const float give = p ? v[2 * k]     : v[2 * k + 1];
                w2[k] = keep + __shfl_xor(give, 2, 64);
            }
        }
        float s;
        {
            const bool p = (lane >> 2) & 1;
            const float keep = p ? w2[1] : w2[0];
            const float give = p ? w2[0] : w2[1];
            s = keep + __shfl_xor(give, 4, 64);
        }
        s += __shfl_xor(s, 8, 64);
        s += __shfl_xor(s, 16, 64);
        s += __shfl_xor(s, 32, 64);

        if (lane < BATCH)
            dist[(size_t)e * BATCH + lane] = GAMMA_F - s;
    }
}

// ---------------------------------------------------------------------------
// Kernel B: out[b,n] = dist[neg[b,n]*8 + b]. dist (3.2MB) is L2-resident.
// 2 outputs/thread: int2 index load, 2 independent gathers, float2 store.
// ---------------------------------------------------------------------------
__global__ __launch_bounds__(256) void kge_gather_kernel(
    const int*  __restrict__ neg,
    const float* __restrict__ dist,
    float* __restrict__ out,
    int nneg)
{
    const int b = blockIdx.y;
    const int n = (blockIdx.x * 256 + threadIdx.x) * 2;
    if (n + 1 < nneg) {
        const int2 idx = *(const int2*)(neg + (size_t)b * nneg + n);
        float2 r;
        r.x = dist[(size_t)idx.x * BATCH + b];
        r.y = dist[(size_t)idx.y * BATCH + b];
        *(float2*)(out + (size_t)b * nneg + n) = r;
    } else if (n < nneg) {
        out[(size_t)b * nneg + n] =
            dist[(size_t)neg[(size_t)b * nneg + n] * BATCH + b];
    }
}

extern "C" void kernel_launch(void* const* d_in, const int* in_sizes, int n_in,
                              void* d_out, int out_size, void* d_ws, size_t ws_size,
                              hipStream_t stream) {
    const float* ent = (const float*)d_in[0];   // [100000, 256] f32
    const float* rel = (const float*)d_in[1];   // [500, 256]    f32
    const int*   pos = (const int*)d_in[2];     // [8, 3]        int32
    const int*   neg = (const int*)d_in[3];     // [8, 100000]   int32
    float* out = (float*)d_out;                 // [8, 100000]   f32

    const int nent = in_sizes[0] / HIDDEN;      // 100000
    const int nneg = in_sizes[3] / BATCH;       // 100000
    float* dist = (float*)d_ws;                 // 3.2 MB (ws is larger)

    // 2048 blocks = 8 blocks/CU = 32 waves/CU (needs VGPR<=64 -> bounds(256,8))
    const int nblocks = 2048;
    const int nwaves = nblocks * 4;
    kge_dist_kernel<<<nblocks, 256, 0, stream>>>(ent, rel, pos, dist,
                                                 nent, nwaves);

    const int npairs = (nneg + 1) / 2;
    dim3 gridB((npairs + 255) / 256, BATCH);
    kge_gather_kernel<<<gridB, 256, 0, stream>>>(neg, dist, out, nneg);
}